// Round 2
// baseline (958.921 us; speedup 1.0000x reference)
//
#include <hip/hip_runtime.h>
#include <math.h>

#define PI_D 3.14159265358979323846264338327950288

// problem constants
#define NPIX 128
#define NFFT 512
#define BATCH 64
#define CSTR 514   // padded column stride (float2) for passBC LDS tile

__device__ __forceinline__ float2 cmulf(float2 a, float2 b) {
    return make_float2(a.x*b.x - a.y*b.y, a.x*b.y + a.y*b.x);
}

// ---------------------------------------------------------------------------
// Stockham radix-2 512-point FFT, 256 threads, LDS ping-pong (row passes).
// twl[a] = exp(-2*pi*i*a/512). isign=+1: forward DFT; isign=-1: unnormalized
// inverse DFT. Data starts in b[cur]; returns buffer index holding the result
// (natural order). Caller must __syncthreads() after loading b[cur].
// ---------------------------------------------------------------------------
__device__ __forceinline__ int fft512f(float2 (*b)[NFFT], const float2* twl,
                                       int t, float isign, int cur)
{
#pragma unroll
    for (int st = 0; st < 9; ++st) {
        const int s = 1 << st;
        const int p = t >> st;
        const int q = t & (s - 1);
        const int m = 256 >> st;
        const float2 a = b[cur][q + s*p];
        const float2 c = b[cur][q + s*(p + m)];
        float2 w = twl[p << st];
        w.y *= isign;
        const float2 dif = make_float2(a.x - c.x, a.y - c.y);
        b[cur^1][q + 2*s*p]     = make_float2(a.x + c.x, a.y + c.y);
        b[cur^1][q + 2*s*p + s] = make_float2(dif.x*w.x - dif.y*w.y,
                                              dif.x*w.y + dif.y*w.x);
        cur ^= 1;
        __syncthreads();
    }
    return cur;
}

// double-precision variant (used only for building H once per launch)
__device__ __forceinline__ int fft512d(double2 (*b)[NFFT], int t, double isign, int cur)
{
    for (int st = 0; st < 9; ++st) {
        const int s = 1 << st;
        const int p = t >> st;
        const int q = t & (s - 1);
        const int m = 256 >> st;
        const double2 a = b[cur][q + s*p];
        const double2 c = b[cur][q + s*(p + m)];
        double sw, cw;
        sincos(isign * (-PI_D/256.0) * (double)(p << st), &sw, &cw);
        const double2 dif = make_double2(a.x - c.x, a.y - c.y);
        b[cur^1][q + 2*s*p]     = make_double2(a.x + c.x, a.y + c.y);
        b[cur^1][q + 2*s*p + s] = make_double2(dif.x*cw - dif.y*sw,
                                               dif.x*sw + dif.y*cw);
        cur ^= 1;
        __syncthreads();
    }
    return cur;
}

// ---------------------------------------------------------------------------
// setup kernels
// ---------------------------------------------------------------------------
__global__ __launch_bounds__(256) void k_twiddle(float2* tw)
{
    int a = threadIdx.x;            // 256 threads
    double s, c;
    sincos(-2.0*PI_D*(double)a/512.0, &s, &c);
    tw[a] = make_float2((float)c, (float)s);
}

// flipped Rayleigh-Sommerfeld kernel, zero-padded into 512x512 (double)
__global__ __launch_bounds__(256) void k_build_w(double2* Wd)
{
    const double WLEN = 5.32e-07, PIX = 1.0e-4, DIST = 0.005;
    int idx = blockIdx.x*blockDim.x + threadIdx.x;   // 512*512 total
    int i = idx >> 9, j = idx & 511;
    double2 v = make_double2(0.0, 0.0);
    if (i < 257 && j < 257) {
        // store w[::-1,::-1]: value at (i,j) is w[256-i][256-j]
        double cx = (double)(128 - i) * PIX;
        double cy = (double)(128 - j) * PIX;
        double r2 = cx*cx + cy*cy + DIST*DIST;
        double r  = sqrt(r2);
        double sc = PIX*PIX*DIST / r2;
        double re_a = 1.0/(2.0*PI_D*r);
        double im_a = -1.0/WLEN;               // 1/(WL*i) = -i/WL
        double sp, cp;
        sincos(2.0*PI_D*r/WLEN, &sp, &cp);
        v.x = sc*(re_a*cp - im_a*sp);
        v.y = sc*(re_a*sp + im_a*cp);
    }
    Wd[idx] = v;
}

__global__ __launch_bounds__(256) void k_dfft_row(const double2* in, double2* out)
{
    __shared__ double2 b[2][NFFT];
    int row = blockIdx.x, t = threadIdx.x;
    b[0][t]       = in[row*NFFT + t];
    b[0][t + 256] = in[row*NFFT + t + 256];
    __syncthreads();
    int cur = fft512d(b, t, 1.0, 0);
    out[row*NFFT + t]       = b[cur][t];
    out[row*NFFT + t + 256] = b[cur][t + 256];
}

// column FFT; writes H TRANSPOSED (Ht[kx*512 + bitrev9(ky)]) as float2 with
// the whole inverse-normalization 1/512^2 folded in. Bit-reversed ky order
// matches the in-place DIF output ordering inside k_passBC.
__global__ __launch_bounds__(256) void k_dfft_col_H(const double2* in, float2* Ht)
{
    __shared__ double2 b[2][NFFT];
    int col = blockIdx.x, t = threadIdx.x;
    b[0][t]       = in[t*NFFT + col];
    b[0][t + 256] = in[(t + 256)*NFFT + col];
    __syncthreads();
    int cur = fft512d(b, t, 1.0, 0);
    const double scale = 1.0/(512.0*512.0);
    unsigned br0 = __brev((unsigned)t) >> 23;          // 9-bit reversal
    unsigned br1 = __brev((unsigned)(t + 256)) >> 23;
    Ht[col*NFFT + br0] = make_float2((float)(b[cur][t].x*scale),
                                     (float)(b[cur][t].y*scale));
    Ht[col*NFFT + br1] = make_float2((float)(b[cur][t+256].x*scale),
                                     (float)(b[cur][t+256].y*scale));
}

// ---------------------------------------------------------------------------
// pass A0: init + first row FFT. grid (128 rows, 64 imgs)
// ---------------------------------------------------------------------------
__global__ __launch_bounds__(256) void k_passA0(const float* x, float2* Abuf,
                                                float2* outc, float* outr,
                                                const float2* twg)
{
    __shared__ float2 b[2][NFFT];
    __shared__ float2 twl[256];
    int row = blockIdx.x, img = blockIdx.y, t = threadIdx.x;
    twl[t] = twg[t];
    float2 z = make_float2(0.f, 0.f);
    float2 val = z;
    if (t < NPIX) {
        float xv = x[(img*NPIX + row)*NPIX + t];
        val = make_float2(xv, 0.f);
        int o = (img*NPIX + row)*NPIX + t;
        if (outc) outc[o] = val;
        else      outr[o] = xv;
    }
    b[0][t]       = val;
    b[0][t + 256] = z;
    __syncthreads();
    int cur = fft512f(b, twl, t, 1.f, 0);
    float2* arow = Abuf + ((size_t)img*NPIX + row)*NFFT;
    arow[t]       = b[cur][t];
    arow[t + 256] = b[cur][t + 256];
}

// ---------------------------------------------------------------------------
// pass BC (tiled): one block = 8 adjacent kx columns of one image.
// Coalesced (128x8) tile load -> in-place DIF (natural->bitrev) -> xH(bitrev)
// -> in-place DIT inverse (bitrev->natural) -> keep spatial rows 128..255,
// coalesced tile store. grid (64 col-tiles, 64 imgs)
// ---------------------------------------------------------------------------
__global__ __launch_bounds__(256) void k_passBC(float2* Abuf, const float2* Ht,
                                                const float2* twg)
{
    __shared__ float2 ld[8*CSTR];
    __shared__ float2 twl[256];
    const int t   = threadIdx.x;
    const int c0  = blockIdx.x * 8;
    const int img = blockIdx.y;
    float2* base = Abuf + (size_t)img*NPIX*NFFT;

    twl[t] = twg[t];

    // H tile -> registers (coalesced: consecutive lanes, consecutive ky)
    float2 hreg[16];
#pragma unroll
    for (int i = 0; i < 16; ++i) {
        int j = t + 256*i;                       // j in [0, 4096)
        hreg[i] = Ht[(size_t)(c0 + (j >> 9))*NFFT + (j & 511)];
    }

    // coalesced tile load (rows 0..127) + zero-pad rows 128..511
#pragma unroll
    for (int i = 0; i < 4; ++i) {
        int idx = t + 256*i;                     // 1024 = 128 rows x 8 cols
        int cc = idx & 7, r = idx >> 3;
        ld[cc*CSTR + r] = base[r*NFFT + c0 + cc];
    }
    {
        int cz = t >> 5, lz = t & 31;
#pragma unroll
        for (int i = 0; i < 12; ++i)             // 384 zeros per column
            ld[cz*CSTR + 128 + lz + 32*i] = make_float2(0.f, 0.f);
    }
    __syncthreads();

    const int c = t >> 5;                        // this thread's FFT column
    const int l = t & 31;                        // 32 threads per column
    float2* col = ld + c*CSTR;

    // forward radix-2 DIF, in place: natural input -> bit-reversed output
#pragma unroll
    for (int lh = 8; lh >= 0; --lh) {
        const int h = 1 << lh;
#pragma unroll
        for (int i = 0; i < 8; ++i) {
            int k  = l + 32*i;                   // butterfly id 0..255
            int j  = k & (h - 1);
            int b0 = (k >> lh) << (lh + 1);
            float2 u = col[b0 + j];
            float2 v = col[b0 + j + h];
            float2 w = twl[j << (8 - lh)];
            col[b0 + j] = make_float2(u.x + v.x, u.y + v.y);
            float2 d = make_float2(u.x - v.x, u.y - v.y);
            col[b0 + j + h] = make_float2(d.x*w.x - d.y*w.y,
                                          d.x*w.y + d.y*w.x);
        }
        __syncthreads();
    }

    // multiply by H (both sides in bit-reversed ky order)
#pragma unroll
    for (int i = 0; i < 16; ++i) {
        int j = t + 256*i;
        int cc = j >> 9, p = j & 511;
        ld[cc*CSTR + p] = cmulf(ld[cc*CSTR + p], hreg[i]);
    }
    __syncthreads();

    // inverse radix-2 DIT, in place: bit-reversed input -> natural output
#pragma unroll
    for (int lh = 0; lh <= 8; ++lh) {
        const int h = 1 << lh;
#pragma unroll
        for (int i = 0; i < 8; ++i) {
            int k  = l + 32*i;
            int j  = k & (h - 1);
            int b0 = (k >> lh) << (lh + 1);
            float2 u = col[b0 + j];
            float2 v = col[b0 + j + h];
            float2 w = twl[j << (8 - lh)];       // conjugate: negate imag
            float2 vw = make_float2(v.x*w.x + v.y*w.y,
                                    v.y*w.x - v.x*w.y);
            col[b0 + j]     = make_float2(u.x + vw.x, u.y + vw.y);
            col[b0 + j + h] = make_float2(u.x - vw.x, u.y - vw.y);
        }
        __syncthreads();
    }

    // keep spatial rows 128..255; coalesced tile store into rows 0..127
#pragma unroll
    for (int i = 0; i < 4; ++i) {
        int idx = t + 256*i;
        int cc = idx & 7, r = idx >> 3;
        base[r*NFFT + c0 + cc] = ld[cc*CSTR + r + 128];
    }
}

// ---------------------------------------------------------------------------
// pass DA (fused): row IFFT + crop + phase mask + output write, then forward
// row FFT of the masked field back into Abuf. grid (128 rows, 64 imgs)
// ---------------------------------------------------------------------------
__global__ __launch_bounds__(256) void k_passDA(float2* Abuf, const float* phases,
                                                float2* outc, float* outr,
                                                const float2* twg, int layer)
{
    __shared__ float2 b[2][NFFT];
    __shared__ float2 twl[256];
    int row = blockIdx.x, img = blockIdx.y, t = threadIdx.x;
    twl[t] = twg[t];
    float2* arow = Abuf + ((size_t)img*NPIX + row)*NFFT;
    b[0][t]       = arow[t];
    b[0][t + 256] = arow[t + 256];
    __syncthreads();
    int cur = fft512f(b, twl, t, -1.f, 0);   // inverse (scale folded into H)

    float2 v = make_float2(0.f, 0.f);
    if (t < NPIX) {
        v = b[cur][t + NPIX];                // crop cols 128..255
        float p  = phases[layer*4096 + (row >> 1)*64 + (t >> 1)];
        float cp = 6.2831853071795864769f * (1.f/(1.f + expf(-p)));
        float sn, cs;
        sincosf(cp, &sn, &cs);
        v = cmulf(v, make_float2(cs, sn));
        int o = (img*NPIX + row)*NPIX + t;
        if (outc) outc[o] = v;
        else      outr[o] = v.x;
    }
    __syncthreads();                          // everyone done reading b[cur]
    b[cur][t]       = (t < NPIX) ? v : make_float2(0.f, 0.f);
    b[cur][t + 256] = make_float2(0.f, 0.f);
    __syncthreads();
    cur = fft512f(b, twl, t, 1.f, cur);       // forward for next layer
    arow[t]       = b[cur][t];
    arow[t + 256] = b[cur][t + 256];
}

// ---------------------------------------------------------------------------
// pass D last: row IFFT + crop + output + |.|^2. grid (128 rows, 64 imgs)
// ---------------------------------------------------------------------------
__global__ __launch_bounds__(256) void k_passDlast(const float2* Abuf,
                                                   float2* outc, float* outr,
                                                   float* outabs, const float2* twg)
{
    __shared__ float2 b[2][NFFT];
    __shared__ float2 twl[256];
    int row = blockIdx.x, img = blockIdx.y, t = threadIdx.x;
    twl[t] = twg[t];
    const float2* arow = Abuf + ((size_t)img*NPIX + row)*NFFT;
    b[0][t]       = arow[t];
    b[0][t + 256] = arow[t + 256];
    __syncthreads();
    int cur = fft512f(b, twl, t, -1.f, 0);
    if (t < NPIX) {
        float2 v = b[cur][t + NPIX];
        int o = (img*NPIX + row)*NPIX + t;
        if (outc) outc[o] = v;
        else      outr[o] = v.x;
        outabs[o] = v.x*v.x + v.y*v.y;
    }
}

// ---------------------------------------------------------------------------
extern "C" void kernel_launch(void* const* d_in, const int* in_sizes, int n_in,
                              void* d_out, int out_size, void* d_ws, size_t ws_size,
                              hipStream_t stream)
{
    const float* x      = (const float*)d_in[0];   // [64,128,128]
    const float* phases = (const float*)d_in[1];   // [5,64,64]
    float* out = (float*)d_out;
    char*  ws  = (char*)d_ws;

    // workspace layout
    float2* tw   = (float2*)ws;                                   // 2 KB
    float2* Ht   = (float2*)(ws + 4096);                          // 2 MB
    float2* Abuf = (float2*)(ws + 4096 + (size_t)NFFT*NFFT*8);    // 33.5 MB
    // double temporaries for H construction alias the (not-yet-used) Abuf
    double2* Wd = (double2*)Abuf;
    double2* Td = (double2*)((char*)Abuf + (size_t)NFFT*NFFT*16);

    // output layout: chunk0 = x_abs (1048576 f32); chunks 1..7 complex fields
    const bool   inter   = (out_size >= 15728640);
    const size_t cstride = inter ? 2097152u : 1048576u;

    k_twiddle   <<<1,    256, 0, stream>>>(tw);
    k_build_w   <<<1024, 256, 0, stream>>>(Wd);
    k_dfft_row  <<<NFFT, 256, 0, stream>>>(Wd, Td);
    k_dfft_col_H<<<NFFT, 256, 0, stream>>>(Td, Ht);

    {
        float* c1 = out + 1048576;
        k_passA0<<<dim3(NPIX, BATCH), 256, 0, stream>>>(
            x, Abuf,
            inter ? (float2*)c1 : nullptr,
            inter ? nullptr : c1, tw);
    }

    for (int step = 0; step < 6; ++step) {
        k_passBC<<<dim3(NFFT/8, BATCH), 256, 0, stream>>>(Abuf, Ht, tw);
        float* chunk = out + 1048576 + (size_t)(step + 1)*cstride;
        if (step < 5) {
            k_passDA<<<dim3(NPIX, BATCH), 256, 0, stream>>>(
                Abuf, phases,
                inter ? (float2*)chunk : nullptr,
                inter ? nullptr : chunk, tw, step);
        } else {
            k_passDlast<<<dim3(NPIX, BATCH), 256, 0, stream>>>(
                Abuf,
                inter ? (float2*)chunk : nullptr,
                inter ? nullptr : chunk,
                out /* x_abs chunk0 */, tw);
        }
    }
}

// Round 3
// 471.844 us; speedup vs baseline: 2.0323x; 2.0323x over previous
//
#include <hip/hip_runtime.h>
#include <math.h>

#define PI_D 3.14159265358979323846264338327950288

#define NPIX 128
#define NFFT 512
#define BATCH 64
#define EXSZ 576          // per-wave exchange region, float2 (72*8, max idx 574)
#define TSTR 130          // passBC staging tile column stride (float2)

__device__ __forceinline__ float2 cmulf(float2 a, float2 b) {
    return make_float2(a.x*b.x - a.y*b.y, a.x*b.y + a.y*b.x);
}
__device__ __forceinline__ float2 cadd(float2 a, float2 b) {
    return make_float2(a.x + b.x, a.y + b.y);
}
__device__ __forceinline__ float2 csub(float2 a, float2 b) {
    return make_float2(a.x - b.x, a.y - b.y);
}

// wave-synchronous LDS: drain DS queue + stop compiler reordering.
#define WSYNC() __asm__ volatile("s_waitcnt lgkmcnt(0)" ::: "memory")

// ---------------------------------------------------------------------------
// in-register 8-point DFT. SGN=-1: X[k]=sum_n x[n] e^{-2pi i nk/8} (forward);
// SGN=+1: conjugate (unnormalized inverse). In-place on x[0..7].
// ---------------------------------------------------------------------------
template<int SGN>
__device__ __forceinline__ void dft8(float2* x)
{
    const float C = 0.70710678118654752440f;
    float2 t0 = cadd(x[0], x[4]), t4 = csub(x[0], x[4]);
    float2 t1 = cadd(x[1], x[5]), t5 = csub(x[1], x[5]);
    float2 t2 = cadd(x[2], x[6]), t6 = csub(x[2], x[6]);
    float2 t3 = cadd(x[3], x[7]), t7 = csub(x[3], x[7]);
    // t5 *= w8^SGN, t6 *= w8^{2 SGN}, t7 *= w8^{3 SGN}
    float2 u5 = make_float2(C*(t5.x - SGN*t5.y), C*(t5.y + SGN*t5.x));
    float2 u6 = make_float2((float)(-SGN)*t6.y, (float)SGN*t6.x);
    float2 u7 = make_float2(-C*(t7.x + SGN*t7.y), C*(SGN*t7.x - t7.y));
    // 4-pt on evens
    float2 s0 = cadd(t0, t2), s2 = csub(t0, t2);
    float2 s1 = cadd(t1, t3), d13 = csub(t1, t3);
    float2 s3 = make_float2((float)(-SGN)*d13.y, (float)SGN*d13.x);
    x[0] = cadd(s0, s1); x[4] = csub(s0, s1);
    x[2] = cadd(s2, s3); x[6] = csub(s2, s3);
    // 4-pt on odds
    float2 s4 = cadd(t4, u6), s6 = csub(t4, u6);
    float2 s5 = cadd(u5, u7), d57 = csub(u5, u7);
    float2 s7 = make_float2((float)(-SGN)*d57.y, (float)SGN*d57.x);
    x[1] = cadd(s4, s5); x[5] = csub(s4, s5);
    x[3] = cadd(s6, s7); x[7] = csub(s6, s7);
}

// apply x[k] *= base^k for k=1..7
__device__ __forceinline__ void twpow(float2* x, float2 base)
{
    float2 w = base;
#pragma unroll
    for (int k = 1; k < 8; ++k) {
        x[k] = cmulf(x[k], w);
        w = cmulf(w, base);
    }
}

// ---------------------------------------------------------------------------
// 512-point FFT, one wave (64 lanes), 8 complex per lane, radix-8 x3.
// Natural order both ends: element index n (or k) = lane + 64*reg.
// ex: per-wave private LDS region of EXSZ float2. Intra-wave sync only.
// ---------------------------------------------------------------------------
__device__ __forceinline__ void fwd512(float2* x, float2* ex, int l)
{
    const int k2 = l & 7, hi = l >> 3;
    float sn, cs, sn2, cs2;
    sincosf((float)(2.0*PI_D/512.0) * (float)l, &sn, &cs);
    sincosf((float)(2.0*PI_D/512.0) * (float)(8*hi), &sn2, &cs2);
    const float2 base  = make_float2(cs,  -sn);    // w512^l
    const float2 base2 = make_float2(cs2, -sn2);   // w512^{8 hi} = w64^hi

    dft8<-1>(x);                 // r -> k2
    twpow(x, base);              // *= w512^{l k2}
    WSYNC();
#pragma unroll
    for (int k = 0; k < 8; ++k) ex[72*k + l] = x[k];
    WSYNC();
#pragma unroll
    for (int k = 0; k < 8; ++k) x[k] = ex[72*k2 + hi + 8*k];
    dft8<-1>(x);                 // b -> c
    twpow(x, base2);             // *= w64^{a c}, a = hi
    WSYNC();
#pragma unroll
    for (int k = 0; k < 8; ++k) ex[k2 + 9*hi + 72*k] = x[k];
    WSYNC();
#pragma unroll
    for (int k = 0; k < 8; ++k) x[k] = ex[k2 + 9*k + 72*hi];
    dft8<-1>(x);                 // a -> d ; X[l + 64 d] in reg d
}

__device__ __forceinline__ void inv512(float2* x, float2* ex, int l)
{
    const int k2 = l & 7, hi = l >> 3;
    float sn, cs, sn2, cs2;
    sincosf((float)(2.0*PI_D/512.0) * (float)l, &sn, &cs);
    sincosf((float)(2.0*PI_D/512.0) * (float)(8*hi), &sn2, &cs2);
    const float2 base  = make_float2(cs,  sn);     // conj
    const float2 base2 = make_float2(cs2, sn2);

    dft8<1>(x);                  // d -> a
    WSYNC();
#pragma unroll
    for (int k = 0; k < 8; ++k) ex[k2 + 9*k + 72*hi] = x[k];
    WSYNC();
#pragma unroll
    for (int k = 0; k < 8; ++k) x[k] = ex[k2 + 9*hi + 72*k];
    twpow(x, base2);             // *= w64^{-a c}
    dft8<1>(x);                  // c -> b
    WSYNC();
#pragma unroll
    for (int k = 0; k < 8; ++k) ex[72*k2 + hi + 8*k] = x[k];
    WSYNC();
#pragma unroll
    for (int k = 0; k < 8; ++k) x[k] = ex[72*k + l];
    twpow(x, base);              // *= w512^{-l k2}
    dft8<1>(x);                  // k2 -> r ; x[l + 64 r] in reg r
}

// ---------------------------------------------------------------------------
// setup: H built in double precision via Stockham ping-pong (one-time cost)
// ---------------------------------------------------------------------------
__device__ __forceinline__ int fft512d(double2 (*b)[NFFT], int t, double isign, int cur)
{
    for (int st = 0; st < 9; ++st) {
        const int s = 1 << st;
        const int p = t >> st;
        const int q = t & (s - 1);
        const int m = 256 >> st;
        const double2 a = b[cur][q + s*p];
        const double2 c = b[cur][q + s*(p + m)];
        double sw, cw;
        sincos(isign * (-PI_D/256.0) * (double)(p << st), &sw, &cw);
        const double2 dif = make_double2(a.x - c.x, a.y - c.y);
        b[cur^1][q + 2*s*p]     = make_double2(a.x + c.x, a.y + c.y);
        b[cur^1][q + 2*s*p + s] = make_double2(dif.x*cw - dif.y*sw,
                                               dif.x*sw + dif.y*cw);
        cur ^= 1;
        __syncthreads();
    }
    return cur;
}

__global__ __launch_bounds__(256) void k_build_w(double2* __restrict__ Wd)
{
    const double WLEN = 5.32e-07, PIX = 1.0e-4, DIST = 0.005;
    int idx = blockIdx.x*blockDim.x + threadIdx.x;   // 512*512 total
    int i = idx >> 9, j = idx & 511;
    double2 v = make_double2(0.0, 0.0);
    if (i < 257 && j < 257) {
        double cx = (double)(128 - i) * PIX;
        double cy = (double)(128 - j) * PIX;
        double r2 = cx*cx + cy*cy + DIST*DIST;
        double r  = sqrt(r2);
        double sc = PIX*PIX*DIST / r2;
        double re_a = 1.0/(2.0*PI_D*r);
        double im_a = -1.0/WLEN;
        double sp, cp;
        sincos(2.0*PI_D*r/WLEN, &sp, &cp);
        v.x = sc*(re_a*cp - im_a*sp);
        v.y = sc*(re_a*sp + im_a*cp);
    }
    Wd[idx] = v;
}

__global__ __launch_bounds__(256) void k_dfft_row(const double2* __restrict__ in,
                                                  double2* __restrict__ out)
{
    __shared__ double2 b[2][NFFT];
    int row = blockIdx.x, t = threadIdx.x;
    b[0][t]       = in[row*NFFT + t];
    b[0][t + 256] = in[row*NFFT + t + 256];
    __syncthreads();
    int cur = fft512d(b, t, 1.0, 0);
    out[row*NFFT + t]       = b[cur][t];
    out[row*NFFT + t + 256] = b[cur][t + 256];
}

// column FFT; Ht[kx*512 + ky] natural order, 1/512^2 folded in.
__global__ __launch_bounds__(256) void k_dfft_col_H(const double2* __restrict__ in,
                                                    float2* __restrict__ Ht)
{
    __shared__ double2 b[2][NFFT];
    int col = blockIdx.x, t = threadIdx.x;
    b[0][t]       = in[t*NFFT + col];
    b[0][t + 256] = in[(t + 256)*NFFT + col];
    __syncthreads();
    int cur = fft512d(b, t, 1.0, 0);
    const double scale = 1.0/(512.0*512.0);
    Ht[col*NFFT + t]       = make_float2((float)(b[cur][t].x*scale),
                                         (float)(b[cur][t].y*scale));
    Ht[col*NFFT + t + 256] = make_float2((float)(b[cur][t+256].x*scale),
                                         (float)(b[cur][t+256].y*scale));
}

// ---------------------------------------------------------------------------
// pass A0: init + first row FFT. block 256 = 4 waves = 4 rows, no barriers.
// ---------------------------------------------------------------------------
__global__ __launch_bounds__(256) void k_passA0(const float* __restrict__ x,
                                                float2* __restrict__ Abuf,
                                                float2* __restrict__ outc,
                                                float*  __restrict__ outr)
{
    __shared__ float2 ex_all[4*EXSZ];
    const int w = threadIdx.x >> 6, l = threadIdx.x & 63;
    const int row = blockIdx.x*4 + w, img = blockIdx.y;
    float2* ex = ex_all + w*EXSZ;

    const float* xr = x + (size_t)(img*NPIX + row)*NPIX;
    float2 v0 = make_float2(xr[l],      0.f);
    float2 v1 = make_float2(xr[l + 64], 0.f);
    size_t o = (size_t)(img*NPIX + row)*NPIX;
    if (outc) { outc[o + l] = v0; outc[o + 64 + l] = v1; }
    else      { outr[o + l] = v0.x; outr[o + 64 + l] = v1.x; }

    float2 X[8];
    X[0] = v0; X[1] = v1;
#pragma unroll
    for (int k = 2; k < 8; ++k) X[k] = make_float2(0.f, 0.f);
    fwd512(X, ex, l);
    float2* arow = Abuf + (size_t)(img*NPIX + row)*NFFT;
#pragma unroll
    for (int d = 0; d < 8; ++d) arow[l + 64*d] = X[d];
}

// ---------------------------------------------------------------------------
// pass BC: 8 columns/block (512 thr = 8 waves, 1 col each). Coalesced tile
// staging in LDS; per-wave register FFTs; H natural order.
// ---------------------------------------------------------------------------
__global__ __launch_bounds__(512) void k_passBC(float2* __restrict__ Abuf,
                                                const float2* __restrict__ Ht)
{
    __shared__ float2 T[8*TSTR];        // 8320 B staging
    __shared__ float2 ex_all[8*EXSZ];   // 36864 B exchange
    const int t = threadIdx.x;
    const int w = t >> 6, l = t & 63;
    const int img = blockIdx.x, c0 = blockIdx.y*8;
    float2* base = Abuf + (size_t)img*NPIX*NFFT;

    // coalesced tile load: (128 rows x 8 cols)
#pragma unroll
    for (int i = 0; i < 2; ++i) {
        int idx = t + 512*i;
        int cc = idx & 7, r = idx >> 3;
        T[cc*TSTR + r] = base[r*NFFT + c0 + cc];
    }
    __syncthreads();

    float2* ex = ex_all + w*EXSZ;
    float2 X[8];
    X[0] = T[w*TSTR + l];
    X[1] = T[w*TSTR + l + 64];
#pragma unroll
    for (int k = 2; k < 8; ++k) X[k] = make_float2(0.f, 0.f);

    fwd512(X, ex, l);
    const float2* Hrow = Ht + (size_t)(c0 + w)*NFFT;
#pragma unroll
    for (int d = 0; d < 8; ++d) X[d] = cmulf(X[d], Hrow[l + 64*d]);
    inv512(X, ex, l);

    // keep spatial rows 128..255 (regs 2,3)
    T[w*TSTR + l]      = X[2];
    T[w*TSTR + l + 64] = X[3];
    __syncthreads();

#pragma unroll
    for (int i = 0; i < 2; ++i) {
        int idx = t + 512*i;
        int cc = idx & 7, r = idx >> 3;
        base[r*NFFT + c0 + cc] = T[cc*TSTR + r];
    }
}

// ---------------------------------------------------------------------------
// pass DA: row IFFT + crop + mask + output, then forward row FFT. No barriers.
// ---------------------------------------------------------------------------
__global__ __launch_bounds__(256) void k_passDA(float2* __restrict__ Abuf,
                                                const float* __restrict__ phases,
                                                float2* __restrict__ outc,
                                                float*  __restrict__ outr,
                                                int layer)
{
    __shared__ float2 ex_all[4*EXSZ];
    const int w = threadIdx.x >> 6, l = threadIdx.x & 63;
    const int row = blockIdx.x*4 + w, img = blockIdx.y;
    float2* ex = ex_all + w*EXSZ;

    float2* arow = Abuf + (size_t)(img*NPIX + row)*NFFT;
    float2 X[8];
#pragma unroll
    for (int d = 0; d < 8; ++d) X[d] = arow[l + 64*d];
    inv512(X, ex, l);

    // crop cols 128..255 -> j = l (reg2), j = 64+l (reg3); apply mask
    const float* ph = phases + layer*4096 + (row >> 1)*64;
    float p0 = ph[(l >> 1)];
    float p1 = ph[32 + (l >> 1)];
    float cp0 = 6.2831853071795864769f * (1.f/(1.f + expf(-p0)));
    float cp1 = 6.2831853071795864769f * (1.f/(1.f + expf(-p1)));
    float s0, c0s, s1, c1s;
    sincosf(cp0, &s0, &c0s);
    sincosf(cp1, &s1, &c1s);
    float2 v0 = cmulf(X[2], make_float2(c0s, s0));
    float2 v1 = cmulf(X[3], make_float2(c1s, s1));

    size_t o = (size_t)(img*NPIX + row)*NPIX;
    if (outc) { outc[o + l] = v0; outc[o + 64 + l] = v1; }
    else      { outr[o + l] = v0.x; outr[o + 64 + l] = v1.x; }

    X[0] = v0; X[1] = v1;
#pragma unroll
    for (int k = 2; k < 8; ++k) X[k] = make_float2(0.f, 0.f);
    fwd512(X, ex, l);
#pragma unroll
    for (int d = 0; d < 8; ++d) arow[l + 64*d] = X[d];
}

// ---------------------------------------------------------------------------
// pass D last: row IFFT + crop + output + |.|^2. No barriers.
// ---------------------------------------------------------------------------
__global__ __launch_bounds__(256) void k_passDlast(const float2* __restrict__ Abuf,
                                                   float2* __restrict__ outc,
                                                   float*  __restrict__ outr,
                                                   float*  __restrict__ outabs)
{
    __shared__ float2 ex_all[4*EXSZ];
    const int w = threadIdx.x >> 6, l = threadIdx.x & 63;
    const int row = blockIdx.x*4 + w, img = blockIdx.y;
    float2* ex = ex_all + w*EXSZ;

    const float2* arow = Abuf + (size_t)(img*NPIX + row)*NFFT;
    float2 X[8];
#pragma unroll
    for (int d = 0; d < 8; ++d) X[d] = arow[l + 64*d];
    inv512(X, ex, l);

    float2 v0 = X[2], v1 = X[3];
    size_t o = (size_t)(img*NPIX + row)*NPIX;
    if (outc) { outc[o + l] = v0; outc[o + 64 + l] = v1; }
    else      { outr[o + l] = v0.x; outr[o + 64 + l] = v1.x; }
    outabs[o + l]      = v0.x*v0.x + v0.y*v0.y;
    outabs[o + 64 + l] = v1.x*v1.x + v1.y*v1.y;
}

// ---------------------------------------------------------------------------
extern "C" void kernel_launch(void* const* d_in, const int* in_sizes, int n_in,
                              void* d_out, int out_size, void* d_ws, size_t ws_size,
                              hipStream_t stream)
{
    const float* x      = (const float*)d_in[0];   // [64,128,128]
    const float* phases = (const float*)d_in[1];   // [5,64,64]
    float* out = (float*)d_out;
    char*  ws  = (char*)d_ws;

    // workspace layout
    float2* Ht   = (float2*)ws;                                   // 2 MB
    float2* Abuf = (float2*)(ws + (size_t)NFFT*NFFT*8);           // 33.5 MB
    // double temporaries for H construction alias the (not-yet-used) Abuf
    double2* Wd = (double2*)Abuf;                                 // 4 MB
    double2* Td = (double2*)((char*)Abuf + (size_t)NFFT*NFFT*16); // 4 MB

    const bool   inter   = (out_size >= 15728640);
    const size_t cstride = inter ? 2097152u : 1048576u;

    k_build_w   <<<1024, 256, 0, stream>>>(Wd);
    k_dfft_row  <<<NFFT, 256, 0, stream>>>(Wd, Td);
    k_dfft_col_H<<<NFFT, 256, 0, stream>>>(Td, Ht);

    {
        float* c1 = out + 1048576;
        k_passA0<<<dim3(NPIX/4, BATCH), 256, 0, stream>>>(
            x, Abuf,
            inter ? (float2*)c1 : nullptr,
            inter ? nullptr : c1);
    }

    for (int step = 0; step < 6; ++step) {
        k_passBC<<<dim3(BATCH, NFFT/8), 512, 0, stream>>>(Abuf, Ht);
        float* chunk = out + 1048576 + (size_t)(step + 1)*cstride;
        if (step < 5) {
            k_passDA<<<dim3(NPIX/4, BATCH), 256, 0, stream>>>(
                Abuf, phases,
                inter ? (float2*)chunk : nullptr,
                inter ? nullptr : chunk, step);
        } else {
            k_passDlast<<<dim3(NPIX/4, BATCH), 256, 0, stream>>>(
                Abuf,
                inter ? (float2*)chunk : nullptr,
                inter ? nullptr : chunk,
                out /* x_abs chunk0 */);
        }
    }
}